// Round 8
// baseline (547.407 us; speedup 1.0000x reference)
//
#include <hip/hip_runtime.h>

#define D_MODEL 2048
#define D_STATE 16
#define BATCH   2048

typedef __attribute__((ext_vector_type(8))) short bf16x8;
typedef __attribute__((ext_vector_type(4))) float f32x4;
typedef __attribute__((ext_vector_type(8))) unsigned short u16x8;

__device__ __forceinline__ unsigned short f2bf(float f) {
  unsigned u = __float_as_uint(f);
  u = (u + 0x7FFFu + ((u >> 16) & 1u)) >> 16;   // RNE
  return (unsigned short)u;
}

__device__ __forceinline__ void cvt8(const float* __restrict__ s, unsigned short* __restrict__ d) {
  f32x4 a = *(const f32x4*)s;
  f32x4 b = *(const f32x4*)(s + 4);
  u16x8 o;
  o[0] = f2bf(a[0]); o[1] = f2bf(a[1]); o[2] = f2bf(a[2]); o[3] = f2bf(a[3]);
  o[4] = f2bf(b[0]); o[5] = f2bf(b[1]); o[6] = f2bf(b[2]); o[7] = f2bf(b[3]);
  *(u16x8*)d = o;
}

// ---- prep: x->bf16, W_Delta->bf16, padded [W_B;W_C;0] bf16, nA = exp(A_log)
__global__ __launch_bounds__(256) void prep_kernel(
    const float* __restrict__ x, const float* __restrict__ wd,
    const float* __restrict__ wb, const float* __restrict__ wc,
    const float* __restrict__ alog,
    unsigned short* __restrict__ x_bf, unsigned short* __restrict__ w_bf,
    unsigned short* __restrict__ wbc, float* __restrict__ nA) {
  int t = blockIdx.x * 256 + threadIdx.x;
  if (t < 524288) {                        // x: 4M elems / 8
    cvt8(x + t * 8, x_bf + t * 8);
  } else if (t < 1048576) {                // W_Delta
    int i = (t - 524288) * 8;
    cvt8(wd + i, w_bf + i);
  } else if (t < 1081344) {                // wbc: 128x2048
    int i = (t - 1048576) * 8;
    int row = i >> 11, col = i & 2047;
    if (row < 16)      cvt8(wb + row * 2048 + col, wbc + i);
    else if (row < 32) cvt8(wc + (row - 16) * 2048 + col, wbc + i);
    else { u16x8 z = {0,0,0,0,0,0,0,0}; *(u16x8*)(wbc + i) = z; }
  } else {                                 // nA: 32768 elems / 4
    int i = (t - 1081344) * 4;
    f32x4 v = *(const f32x4*)(alog + i);
    f32x4 o;
    o[0] = __expf(v[0]); o[1] = __expf(v[1]); o[2] = __expf(v[2]); o[3] = __expf(v[3]);
    *(f32x4*)(nA + i) = o;
  }
}

// ---- bf16 MFMA GEMM, 128x128 tile, BK=64, 2-phase LDS double-buffer,
// T2 chunk-swizzle (chunk ^= row&7) via pre-swizzled global source.
// blockIdx.y in [0,16): Delta = softplus(x @ W_Delta^T + b)
// blockIdx.y == 16   : BC    = x @ WBC^T
__global__ __launch_bounds__(256) void gemm_kernel(
    const unsigned short* __restrict__ Abf,   // 2048 x 2048 (x, bf16)
    const unsigned short* __restrict__ Wbf,   // 2048 x 2048 (W_Delta, bf16)
    const unsigned short* __restrict__ WBC,   // 128 x 2048
    const float* __restrict__ bias,
    float* __restrict__ Delta,                // 2048 x 2048
    float* __restrict__ BC) {                 // 2048 x 128
  __shared__ __align__(16) unsigned short lA[2][8192];   // [buf][128 rows x 64 k]
  __shared__ __align__(16) unsigned short lB[2][8192];

  const int tid = threadIdx.x;
  const bool isBC = (blockIdx.y == 16);
  const int brow = blockIdx.x * 128;
  const int bcol = isBC ? 0 : blockIdx.y * 128;
  const unsigned short* Bsrc = isBC ? WBC : (Wbf + (size_t)bcol * 2048);
  const unsigned short* Asrc = Abf + (size_t)brow * 2048;

  const int lane = tid & 63;
  const int wid = tid >> 6;
  const int wr = wid >> 1, wcid = wid & 1;
  const int fr = lane & 15;     // fragment row/col
  const int kg = lane >> 4;     // k-group

  // staging: 16KB tile = 1024 chunks of 16B; call i covers ci = i*256 + tid.
  // stored chunk (r, cs) holds logical chunk c = cs ^ (r&7)  [T2 swizzle]
  int srcoff[4];
#pragma unroll
  for (int i = 0; i < 4; ++i) {
    int ci = i * 256 + tid;
    int r = ci >> 3, cs = ci & 7;
    int c = cs ^ (r & 7);
    srcoff[i] = r * 2048 + c * 8;
  }
  const int ldsb = (tid >> 6) << 10;   // wave-uniform LDS byte base

  f32x4 acc[4][4];
#pragma unroll
  for (int m = 0; m < 4; ++m)
#pragma unroll
    for (int n = 0; n < 4; ++n) acc[m][n] = (f32x4){0.f, 0.f, 0.f, 0.f};

#define STAGE(buf, k0)                                                          \
  do {                                                                          \
    _Pragma("unroll")                                                           \
    for (int i = 0; i < 4; ++i)                                                 \
      __builtin_amdgcn_global_load_lds(                                         \
          (const __attribute__((address_space(1))) void*)(Asrc + (size_t)srcoff[i] + (k0)), \
          (__attribute__((address_space(3))) void*)((char*)lA[buf] + i * 4096 + ldsb), \
          16, 0, 0);                                                            \
    _Pragma("unroll")                                                           \
    for (int i = 0; i < 4; ++i)                                                 \
      __builtin_amdgcn_global_load_lds(                                         \
          (const __attribute__((address_space(1))) void*)(Bsrc + (size_t)srcoff[i] + (k0)), \
          (__attribute__((address_space(3))) void*)((char*)lB[buf] + i * 4096 + ldsb), \
          16, 0, 0);                                                            \
  } while (0)

  STAGE(0, 0);
  asm volatile("s_waitcnt vmcnt(0)" ::: "memory");
  __builtin_amdgcn_s_barrier();
  int cur = 0;
#pragma unroll 1
  for (int t = 0; t < 32; ++t) {
    if (t < 31) STAGE(cur ^ 1, (t + 1) * 64);   // prefetch next K-tile

    bf16x8 fa[2][4], fb[2][4];
#pragma unroll
    for (int m = 0; m < 4; ++m) {
      int row = wr * 64 + m * 16 + fr;
#pragma unroll
      for (int kk = 0; kk < 2; ++kk)
        fa[kk][m] = *(const bf16x8*)((const char*)lA[cur] + row * 128 +
                                     ((((kk << 2) + kg) ^ (row & 7)) << 4));
    }
#pragma unroll
    for (int n = 0; n < 4; ++n) {
      int row = wcid * 64 + n * 16 + fr;
#pragma unroll
      for (int kk = 0; kk < 2; ++kk)
        fb[kk][n] = *(const bf16x8*)((const char*)lB[cur] + row * 128 +
                                     ((((kk << 2) + kg) ^ (row & 7)) << 4));
    }
#pragma unroll
    for (int kk = 0; kk < 2; ++kk)
#pragma unroll
      for (int m = 0; m < 4; ++m)
#pragma unroll
        for (int n = 0; n < 4; ++n)
          acc[m][n] = __builtin_amdgcn_mfma_f32_16x16x32_bf16(fa[kk][m], fb[kk][n], acc[m][n], 0, 0, 0);

    asm volatile("s_waitcnt vmcnt(0)" ::: "memory");   // prefetch landed
    __builtin_amdgcn_s_barrier();                      // all waves done reading cur
    cur ^= 1;
  }
#undef STAGE

  // epilogue: C/D layout col=lane&15, row=(lane>>4)*4+q  [m89-verified]
  const int rq = kg * 4;
#pragma unroll
  for (int m = 0; m < 4; ++m) {
    int grow = brow + wr * 64 + m * 16 + rq;
#pragma unroll
    for (int n = 0; n < 4; ++n) {
      int gcol = bcol + wcid * 64 + n * 16 + fr;
      if (!isBC) {
        float bv = bias[gcol];
#pragma unroll
        for (int q = 0; q < 4; ++q) {
          float v = acc[m][n][q] + bv;
          v = fmaxf(v, 0.f) + log1pf(__expf(-fabsf(v)));   // softplus
          Delta[(size_t)(grow + q) * 2048 + gcol] = v;
        }
      } else {
#pragma unroll
        for (int q = 0; q < 4; ++q)
          BC[(size_t)(grow + q) * 128 + gcol] = acc[m][n][q];
      }
    }
  }
}

// ---- pointwise state update: 2 lanes per (b,d), 8 states (2 f32x4) each
__global__ __launch_bounds__(256) void pointwise_kernel(
    const float* __restrict__ x, const float* __restrict__ sp,
    const float* __restrict__ nA, const float* __restrict__ BCb,
    const float* __restrict__ Delta, const float* __restrict__ Dp,
    float* __restrict__ y, float* __restrict__ st) {
  int t = blockIdx.x * 256 + threadIdx.x;   // B*D*2 = 8,388,608 threads
  int sg = t & 1;
  int d = (t >> 1) & 2047;
  int b = t >> 12;
  int bd = (b << 11) + d;
  float delta = Delta[bd];
  float xv = x[bd];
  float dx = delta * xv;
  const f32x4* spp = (const f32x4*)sp + ((size_t)t << 1);
  f32x4 s0 = __builtin_nontemporal_load(spp);
  f32x4 s1 = __builtin_nontemporal_load(spp + 1);
  const f32x4* ap = (const f32x4*)nA + ((d << 2) + (sg << 1));
  f32x4 a0 = ap[0], a1 = ap[1];
  const f32x4* bp = (const f32x4*)BCb + ((b << 5) + (sg << 1));
  f32x4 b0 = bp[0], b1 = bp[1];
  f32x4 c0 = bp[4], c1 = bp[5];     // C_t at col offset 16 = 4 f32x4s
  f32x4 r0, r1;
  r0[0] = __expf(-delta * a0[0]) * s0[0] + dx * b0[0];
  r0[1] = __expf(-delta * a0[1]) * s0[1] + dx * b0[1];
  r0[2] = __expf(-delta * a0[2]) * s0[2] + dx * b0[2];
  r0[3] = __expf(-delta * a0[3]) * s0[3] + dx * b0[3];
  r1[0] = __expf(-delta * a1[0]) * s1[0] + dx * b1[0];
  r1[1] = __expf(-delta * a1[1]) * s1[1] + dx * b1[1];
  r1[2] = __expf(-delta * a1[2]) * s1[2] + dx * b1[2];
  r1[3] = __expf(-delta * a1[3]) * s1[3] + dx * b1[3];
  f32x4* stp = (f32x4*)st + ((size_t)t << 1);
  __builtin_nontemporal_store(r0, stp);
  __builtin_nontemporal_store(r1, stp + 1);
  float p = r0[0] * c0[0] + r0[1] * c0[1] + r0[2] * c0[2] + r0[3] * c0[3]
          + r1[0] * c1[0] + r1[1] * c1[1] + r1[2] * c1[2] + r1[3] * c1[3];
  p += __shfl_xor(p, 1, 2);
  if (sg == 0) y[bd] = p + Dp[d] * xv;
}

extern "C" void kernel_launch(void* const* d_in, const int* in_sizes, int n_in,
                              void* d_out, int out_size, void* d_ws, size_t ws_size,
                              hipStream_t stream) {
  const float* x    = (const float*)d_in[0];
  const float* sp   = (const float*)d_in[1];
  const float* alog = (const float*)d_in[2];
  const float* wb   = (const float*)d_in[3];
  const float* wc   = (const float*)d_in[4];
  const float* wd   = (const float*)d_in[5];
  const float* bdel = (const float*)d_in[6];
  const float* dp   = (const float*)d_in[7];
  float* y  = (float*)d_out;                              // (B, D)
  float* st = (float*)d_out + (size_t)BATCH * D_MODEL;    // (B, D, S)

  char* ws = (char*)d_ws;
  unsigned short* x_bf = (unsigned short*)ws;               // 8 MB
  unsigned short* w_bf = (unsigned short*)(ws + 8388608);   // 8 MB
  unsigned short* wbc  = (unsigned short*)(ws + 16777216);  // 512 KB
  float* Delta = (float*)(ws + 17301504);                   // 16 MB
  float* BC    = (float*)(ws + 34078720);                   // 1 MB
  float* nA    = (float*)(ws + 35127296);                   // 128 KB

  prep_kernel<<<4256, 256, 0, stream>>>(x, wd, wb, wc, alog, x_bf, w_bf, wbc, nA);
  gemm_kernel<<<dim3(16, 17), 256, 0, stream>>>(x_bf, w_bf, wbc, bdel, Delta, BC);
  pointwise_kernel<<<32768, 256, 0, stream>>>(x, sp, nA, BC, Delta, dp, y, st);
}